// Round 1
// baseline (439.642 us; speedup 1.0000x reference)
//
#include <hip/hip_runtime.h>
#include <hip/hip_bf16.h>
#include <math.h>

#define B_   4
#define S_   4096
#define D_   1024
#define M_   (B_*S_)        // 16384 rows
#define NCAT (4*D_)         // 4096 concat projection cols

#define NCHUNK 128          // scan chunks along S
#define CHLEN  (S_/NCHUNK)  // 32

typedef __bf16 bf16x8 __attribute__((ext_vector_type(8)));
typedef float  f32x4  __attribute__((ext_vector_type(4)));

__device__ __forceinline__ ushort f2bf(float f) {
  union { float f; uint u; } v; v.f = f;
  uint u = v.u;
  return (ushort)((u + 0x7FFFu + ((u >> 16) & 1u)) >> 16);  // RNE
}
__device__ __forceinline__ float bf2f(uint bits16) {
  union { uint u; float f; } v; v.u = bits16 << 16;
  return v.f;
}

// global -> LDS direct (16B per lane). LDS dest must be linear in lane order.
#define GLL(g, l) __builtin_amdgcn_global_load_lds( \
  (const __attribute__((address_space(1))) uint32_t*)(uintptr_t)(g), \
  (__attribute__((address_space(3))) uint32_t*)(uint32_t)(uintptr_t)(l), 16, 0, 0)

// ---------------- K0: conversions ----------------
__global__ void k_cvt_f2b4(const float* __restrict__ in, ushort* __restrict__ out, int n4) {
  int i = blockIdx.x * blockDim.x + threadIdx.x;
  if (i >= n4) return;
  const float4 v = ((const float4*)in)[i];
  uint2 o;
  o.x = (uint)f2bf(v.x) | ((uint)f2bf(v.y) << 16);
  o.y = (uint)f2bf(v.z) | ((uint)f2bf(v.w) << 16);
  ((uint2*)out)[i] = o;
}

// Wcat rows: [0,1024)=W_delta, [1024,2048)=W_select, [2048,3072)=W_in, [3072,4096)=W_gate
__global__ void k_build_wcat(const float* __restrict__ wdel, const float* __restrict__ wsel,
                             const float* __restrict__ win,  const float* __restrict__ wgat,
                             ushort* __restrict__ wcat) {
  int i = blockIdx.x * blockDim.x + threadIdx.x;  // one per 4 elements
  int E = i * 4;
  int row = E >> 10;
  int col = E & 1023;
  const float* src = (row < 1024) ? wdel : (row < 2048) ? wsel : (row < 3072) ? win : wgat;
  const float4 v = *(const float4*)&src[(size_t)(row & 1023) * 1024 + col];
  uint2 o;
  o.x = (uint)f2bf(v.x) | ((uint)f2bf(v.y) << 16);
  o.y = (uint)f2bf(v.z) | ((uint)f2bf(v.w) << 16);
  *(uint2*)&wcat[E] = o;
}

__global__ void k_abase(const float* __restrict__ log_a, float* __restrict__ abase) {
  int i = blockIdx.x * blockDim.x + threadIdx.x;
  if (i < D_) abase[i] = 1.f / (1.f + __expf(-log_a[i]));
}

// ---------------- GEMM: C[m][n] = sum_k A[m][k]*B[n][k]  (B^T layout) ----------------
// MODE 0: N=NCAT, epilogue -> decay/sig(select)/tanh(in)/gate (bf16 arrays, [M][1024] each)
// MODE 1: plain fp32 store to outf[M][N]
#define BM 128
#define BN 128
#define BKK 32

template<int MODE>
__global__ __launch_bounds__(256, 2) void gemm_bt(
    const ushort* __restrict__ Ab, const ushort* __restrict__ Bb,
    int N, int K,
    float* __restrict__ outf,
    ushort* __restrict__ dec, ushort* __restrict__ ssl,
    ushort* __restrict__ tin, ushort* __restrict__ gat,
    const float* __restrict__ abase)
{
  __shared__ ushort lds_a[BM*BKK];
  __shared__ ushort lds_b[BN*BKK];
  const int nbx  = N / BN;
  const int brow = blockIdx.x / nbx;
  const int bcol = blockIdx.x % nbx;
  const int t    = threadIdx.x;
  const int lane = t & 63;
  const int wid  = t >> 6;
  const int wr = wid >> 1, wc = wid & 1;
  const int l15 = lane & 15, lhi = lane >> 4;

  f32x4 acc[4][4] = {};

  // staging: thread t loads row r0=t>>2, cols (t&3)*8..+8; linear LDS dest = t*8 elems
  const int r0 = t >> 2;
  const int c0 = (t & 3) << 3;
  const ushort* agp = Ab + (size_t)(brow*BM + r0) * K + c0;
  const ushort* bgp = Bb + (size_t)(bcol*BN + r0) * K + c0;
  ushort* la = &lds_a[t * 8];
  ushort* lb = &lds_b[t * 8];
  const size_t rowskip = (size_t)64 * K;

  for (int k0 = 0; k0 < K; k0 += BKK) {
    GLL(agp + k0,           la);
    GLL(agp + k0 + rowskip, la + 2048);
    GLL(bgp + k0,           lb);
    GLL(bgp + k0 + rowskip, lb + 2048);
    __syncthreads();
    bf16x8 af[4], bfr[4];
#pragma unroll
    for (int m = 0; m < 4; ++m)
      af[m] = *(const bf16x8*)&lds_a[(wr*64 + m*16 + l15)*BKK + lhi*8];
#pragma unroll
    for (int n = 0; n < 4; ++n)
      bfr[n] = *(const bf16x8*)&lds_b[(wc*64 + n*16 + l15)*BKK + lhi*8];
#pragma unroll
    for (int m = 0; m < 4; ++m)
#pragma unroll
      for (int n = 0; n < 4; ++n)
        acc[m][n] = __builtin_amdgcn_mfma_f32_16x16x32_bf16(af[m], bfr[n], acc[m][n], 0, 0, 0);
    __syncthreads();
  }

  const int gnb = bcol*BN + wc*64;
  const int gmb = brow*BM + wr*64;

  if constexpr (MODE == 0) {
    const int j = gnb >> 10;  // block-uniform: which projection
    ushort* dst = (j == 0) ? dec : (j == 1) ? ssl : (j == 2) ? tin : gat;
#pragma unroll
    for (int n = 0; n < 4; ++n) {
      const int gn = gnb + n*16 + l15;
      const int e  = gn & (D_-1);
      const float ab = (j == 0) ? abase[e] : 0.f;
#pragma unroll
      for (int m = 0; m < 4; ++m) {
        const int gm0 = gmb + m*16 + lhi*4;
#pragma unroll
        for (int r = 0; r < 4; ++r) {
          float z = acc[m][n][r];
          float val;
          if (j == 0) {
            // delta = max(softplus(z),1e-4); decay = exp(-delta*a)
            float sp = fmaxf(z, 0.f) + log1pf(__expf(-fabsf(z)));
            sp = fmaxf(sp, 1e-4f);
            val = __expf(-sp * ab);
          } else if (j == 2) {
            float tt = __expf(-2.f * fabsf(z));
            val = (1.f - tt) / (1.f + tt);
            val = (z < 0.f) ? -val : val;
          } else {
            val = 1.f / (1.f + __expf(-z));
          }
          dst[(size_t)(gm0 + r) * D_ + e] = f2bf(val);
        }
      }
    }
  } else {
#pragma unroll
    for (int n = 0; n < 4; ++n) {
      const int gn = gnb + n*16 + l15;
#pragma unroll
      for (int m = 0; m < 4; ++m) {
        const int gm0 = gmb + m*16 + lhi*4;
#pragma unroll
        for (int r = 0; r < 4; ++r)
          outf[(size_t)(gm0 + r) * N + gn] = acc[m][n][r];
      }
    }
  }
}

// ---------------- scan (3-phase chunked, exact affine composition) ----------------
// Phase A: per (b, chunk, e): local P = prod(decay), L = local state from 0-init.
__global__ __launch_bounds__(512) void k_scanA(
    const ushort* __restrict__ dec, const ushort* __restrict__ ssl, const ushort* __restrict__ tin,
    float* __restrict__ cP, float* __restrict__ cL)
{
  const int t  = threadIdx.x;                 // covers e in pairs: e2 = 2t
  const int c  = blockIdx.x & (NCHUNK-1);
  const int b  = blockIdx.x >> 7;
  const int e2 = t * 2;
  size_t base = ((size_t)b * S_ + (size_t)c * CHLEN) * D_ + e2;
  float P0 = 1.f, P1 = 1.f, L0 = 0.f, L1 = 0.f;
  for (int i = 0; i < CHLEN; ++i) {
    const uint dv = *(const uint*)(dec + base);
    const uint sv = *(const uint*)(ssl + base);
    const uint tv = *(const uint*)(tin + base);
    float d0 = bf2f(dv & 0xffffu), d1 = bf2f(dv >> 16);
    float u0 = bf2f(sv & 0xffffu) * bf2f(tv & 0xffffu);
    float u1 = bf2f(sv >> 16)     * bf2f(tv >> 16);
    P0 *= d0; L0 = fmaf(d0, L0, u0);
    P1 *= d1; L1 = fmaf(d1, L1, u1);
    base += D_;
  }
  size_t o = ((size_t)b * NCHUNK + c) * D_ + e2;
  cP[o] = P0; cP[o+1] = P1; cL[o] = L0; cL[o+1] = L1;
}

// Phase B: serial combine of chunk summaries per channel -> carry entering each chunk.
__global__ __launch_bounds__(512) void k_scanB(
    const float* __restrict__ cP, const float* __restrict__ cL, float* __restrict__ carry)
{
  const int idx = blockIdx.x * blockDim.x + threadIdx.x;  // 0..B_*D_-1
  const int b = idx >> 10, e = idx & 1023;
  float st = 0.f;
  size_t base = (size_t)b * NCHUNK * D_ + e;
  for (int c = 0; c < NCHUNK; ++c) {
    size_t o = base + (size_t)c * D_;
    carry[o] = st;
    st = fmaf(cP[o], st, cL[o]);
  }
}

// Phase C: replay chunk with true carry; fuse gate multiply; write bf16 "out" for final GEMM.
__global__ __launch_bounds__(512) void k_scanC(
    const ushort* __restrict__ dec, const ushort* __restrict__ ssl, const ushort* __restrict__ tin,
    const ushort* __restrict__ gat, const float* __restrict__ carry, ushort* __restrict__ outb)
{
  const int t  = threadIdx.x;
  const int c  = blockIdx.x & (NCHUNK-1);
  const int b  = blockIdx.x >> 7;
  const int e2 = t * 2;
  size_t co = ((size_t)b * NCHUNK + c) * D_ + e2;
  float s0 = carry[co], s1 = carry[co+1];
  size_t base = ((size_t)b * S_ + (size_t)c * CHLEN) * D_ + e2;
  for (int i = 0; i < CHLEN; ++i) {
    const uint dv = *(const uint*)(dec + base);
    const uint sv = *(const uint*)(ssl + base);
    const uint tv = *(const uint*)(tin + base);
    const uint gv = *(const uint*)(gat + base);
    float u0 = bf2f(sv & 0xffffu) * bf2f(tv & 0xffffu);
    float u1 = bf2f(sv >> 16)     * bf2f(tv >> 16);
    s0 = fmaf(bf2f(dv & 0xffffu), s0, u0);
    s1 = fmaf(bf2f(dv >> 16),     s1, u1);
    float o0 = bf2f(gv & 0xffffu) * s0;
    float o1 = bf2f(gv >> 16)     * s1;
    *(uint*)(outb + base) = (uint)f2bf(o0) | ((uint)f2bf(o1) << 16);
    base += D_;
  }
}

// ---------------- launcher ----------------
extern "C" void kernel_launch(void* const* d_in, const int* in_sizes, int n_in,
                              void* d_out, int out_size, void* d_ws, size_t ws_size,
                              hipStream_t stream) {
  const float* x     = (const float*)d_in[0];
  const float* W_in  = (const float*)d_in[1];
  const float* W_sel = (const float*)d_in[2];
  const float* W_gat = (const float*)d_in[3];
  const float* W_out = (const float*)d_in[4];
  const float* W_del = (const float*)d_in[5];
  const float* log_a = (const float*)d_in[6];
  float* y = (float*)d_out;

  char* ws = (char*)d_ws;
  size_t off = 0;
  auto alloc = [&](size_t bytes) { char* p = ws + off; off += (bytes + 255) & ~(size_t)255; return p; };
  ushort* xbf   = (ushort*)alloc((size_t)M_ * D_ * 2);   // reused as outb after K1
  ushort* wcat  = (ushort*)alloc((size_t)NCAT * D_ * 2);
  ushort* woutb = (ushort*)alloc((size_t)D_ * D_ * 2);
  ushort* dec   = (ushort*)alloc((size_t)M_ * D_ * 2);
  ushort* ssl   = (ushort*)alloc((size_t)M_ * D_ * 2);
  ushort* tin   = (ushort*)alloc((size_t)M_ * D_ * 2);
  ushort* gat   = (ushort*)alloc((size_t)M_ * D_ * 2);
  float*  cP    = (float*)alloc((size_t)B_ * NCHUNK * D_ * 4);
  float*  cL    = (float*)alloc((size_t)B_ * NCHUNK * D_ * 4);
  float*  carry = (float*)alloc((size_t)B_ * NCHUNK * D_ * 4);
  float*  abase = (float*)alloc(D_ * 4);
  ushort* outb  = xbf;  // alias: x_bf16 dead after projection GEMM

  // K0: dtype conversions
  k_cvt_f2b4<<<(M_*D_/4 + 255)/256, 256, 0, stream>>>(x, xbf, M_*D_/4);
  k_build_wcat<<<(NCAT*D_/4 + 255)/256, 256, 0, stream>>>(W_del, W_sel, W_in, W_gat, wcat);
  k_cvt_f2b4<<<(D_*D_/4 + 255)/256, 256, 0, stream>>>(W_out, woutb, D_*D_/4);
  k_abase<<<(D_+255)/256, 256, 0, stream>>>(log_a, abase);

  // K1: fused 4-projection GEMM + activation epilogue
  gemm_bt<0><<<(M_/BM) * (NCAT/BN), 256, 0, stream>>>(
      xbf, wcat, NCAT, D_, nullptr, dec, ssl, tin, gat, abase);

  // K2: chunked scan
  k_scanA<<<B_*NCHUNK, 512, 0, stream>>>(dec, ssl, tin, cP, cL);
  k_scanB<<<(B_*D_)/512, 512, 0, stream>>>(cP, cL, carry);
  k_scanC<<<B_*NCHUNK, 512, 0, stream>>>(dec, ssl, tin, gat, carry, outb);

  // K3: output GEMM -> fp32 y
  gemm_bt<1><<<(M_/BM) * (D_/BN), 256, 0, stream>>>(
      outb, woutb, D_, D_, y, nullptr, nullptr, nullptr, nullptr, nullptr);
}

// Round 2
// 335.560 us; speedup vs baseline: 1.3102x; 1.3102x over previous
//
#include <hip/hip_runtime.h>
#include <hip/hip_bf16.h>
#include <math.h>

#define B_   4
#define S_   4096
#define D_   1024
#define M_   (B_*S_)        // 16384 rows
#define NCAT (4*D_)         // 4096 concat projection cols
#define KDIM 1024
#define NT   (KDIM/32)      // 32 K-tiles of BK=32

#define NCHUNK 128          // scan chunks along S
#define CHLEN  (S_/NCHUNK)  // 32

typedef __bf16 bf16x8 __attribute__((ext_vector_type(8)));
typedef float  f32x4  __attribute__((ext_vector_type(4)));
typedef ushort ushort8v __attribute__((ext_vector_type(8)));

__device__ __forceinline__ ushort f2bf(float f) {
  union { float f; uint u; } v; v.f = f;
  uint u = v.u;
  return (ushort)((u + 0x7FFFu + ((u >> 16) & 1u)) >> 16);  // RNE
}
__device__ __forceinline__ float bf2f(uint bits16) {
  union { uint u; float f; } v; v.u = bits16 << 16;
  return v.f;
}

// global -> LDS direct (16B per lane). LDS dest linear: wave-uniform base + lane*16.
#define GLL(g, l) __builtin_amdgcn_global_load_lds( \
  (const __attribute__((address_space(1))) uint32_t*)(uintptr_t)(g), \
  (__attribute__((address_space(3))) uint32_t*)(uint32_t)(uintptr_t)(l), 16, 0, 0)

// 16B-chunk XOR swizzle within a 64B row of a [256][32]-bf16 tile
__device__ __forceinline__ int swz(int row, int kc) { return kc ^ ((row >> 1) & 3); }

// ---------------- K0: conversions ----------------
__global__ void k_cvt_f2b4(const float* __restrict__ in, ushort* __restrict__ out, int n4) {
  int i = blockIdx.x * blockDim.x + threadIdx.x;
  if (i >= n4) return;
  const float4 v = ((const float4*)in)[i];
  uint2 o;
  o.x = (uint)f2bf(v.x) | ((uint)f2bf(v.y) << 16);
  o.y = (uint)f2bf(v.z) | ((uint)f2bf(v.w) << 16);
  ((uint2*)out)[i] = o;
}

// Interleaved Wcat: row n -> proj p=(n>>4)&3 of channel e=(n>>6)*16+(n&15)
// (each 64-row group = 16 channels x {delta,select,in,gate})
__global__ void k_build_wcat(const float* __restrict__ wdel, const float* __restrict__ wsel,
                             const float* __restrict__ win,  const float* __restrict__ wgat,
                             ushort* __restrict__ wcat) {
  int i = blockIdx.x * blockDim.x + threadIdx.x;  // one per 4 elements
  int E = i * 4;
  int n   = E >> 10;
  int col = E & 1023;
  int p = (n >> 4) & 3;
  int e = ((n >> 6) << 4) + (n & 15);
  const float* src = (p == 0) ? wdel : (p == 1) ? wsel : (p == 2) ? win : wgat;
  const float4 v = *(const float4*)&src[(size_t)e * 1024 + col];
  uint2 o;
  o.x = (uint)f2bf(v.x) | ((uint)f2bf(v.y) << 16);
  o.y = (uint)f2bf(v.z) | ((uint)f2bf(v.w) << 16);
  *(uint2*)&wcat[E] = o;
}

__global__ void k_abase(const float* __restrict__ log_a, float* __restrict__ abase) {
  int i = blockIdx.x * blockDim.x + threadIdx.x;
  if (i < D_) abase[i] = 1.f / (1.f + __expf(-log_a[i]));
}

// ---------------- 256x256 GEMM, BK=32, ring-3 LDS, counted vmcnt ----------------
// C[m][n] = sum_k A[m][k]*B[n][k].
// MODE 0: N=4096 interleaved Wcat; epilogue computes dec/u/gate and stores via LDS.
// MODE 1: N=1024 plain; fp32 store to outf.
template<int MODE>
__global__ __launch_bounds__(512, 2) void gemm8(
    const ushort* __restrict__ Ab, const ushort* __restrict__ Bb, int nbn,
    float* __restrict__ outf,
    ushort* __restrict__ dec, ushort* __restrict__ uu, ushort* __restrict__ gat,
    const float* __restrict__ abase)
{
  // ring of 3 slots; each slot: A [256][32] bf16 (16KB) + B [256][32] bf16 (16KB)
  __shared__ ushort lds[3 * 16384];

  const int bid  = blockIdx.x;
  const int brow = bid / nbn;
  const int bcol = bid % nbn;
  const int t    = threadIdx.x;
  const int lane = t & 63;
  const int w    = t >> 6;          // 8 waves: wm in {0,1}, wn in {0..3}
  const int wm = w >> 2, wn = w & 3;
  const int l15 = lane & 15, lhi = lane >> 4;

  // ---- staging addressing: thread covers 16B chunks o0,o1 of the 1024-chunk tile
  const int o0 = ((w * 2 + 0) << 6) + lane;
  const int o1 = ((w * 2 + 1) << 6) + lane;
  const int r0s = o0 >> 2, kc0 = o0 & 3;
  const int r1s = o1 >> 2, kc1 = o1 & 3;
  const ushort* a0p = Ab + (size_t)(brow * 256 + r0s) * KDIM + (swz(r0s, kc0) << 3);
  const ushort* a1p = Ab + (size_t)(brow * 256 + r1s) * KDIM + (swz(r1s, kc1) << 3);
  const ushort* b0p = Bb + (size_t)(bcol * 256 + r0s) * KDIM + (swz(r0s, kc0) << 3);
  const ushort* b1p = Bb + (size_t)(bcol * 256 + r1s) * KDIM + (swz(r1s, kc1) << 3);
  const int da0 = o0 * 8, da1 = o1 * 8;            // ushort offsets in slot (A)
  const int db0 = 8192 + o0 * 8, db1 = 8192 + o1 * 8;  // (B)

#define STAGE_A(sl, kt) do { GLL(a0p + (kt)*32, &lds[(sl)*16384 + da0]); \
                             GLL(a1p + (kt)*32, &lds[(sl)*16384 + da1]); } while (0)
#define STAGE_B(sl, kt) do { GLL(b0p + (kt)*32, &lds[(sl)*16384 + db0]); \
                             GLL(b1p + (kt)*32, &lds[(sl)*16384 + db1]); } while (0)

  // ---- fragment read offsets (swizzled). (row>>1)&3 == (l15>>1)&3 since bases %16==0
  const int kswz  = lhi ^ ((l15 >> 1) & 3);
  const int aoffb = ((wm * 128 + l15) * 4 + kswz) * 8;          // + mf*512
  const int boffb = 8192 + ((wn * 64 + l15) * 4 + kswz) * 8;    // + nf*512

  f32x4 acc[8][4] = {};

  // ---- prologue: stage tiles 0,1 into slots 0,1; wait tile 0 (keep 4 in flight)
  STAGE_A(0, 0); STAGE_B(0, 0);
  STAGE_A(1, 1); STAGE_B(1, 1);
  asm volatile("s_waitcnt vmcnt(4)" ::: "memory");
  __builtin_amdgcn_s_barrier();

  int sR = 0;
  for (int T = 0; T < NT; ++T) {
    const int kt = (T + 2 < NT) ? T + 2 : NT - 1;   // clamp: keeps vmcnt accounting uniform
    const int sW = (sR == 0) ? 2 : sR - 1;          // (sR+2)%3
    const ushort* As = &lds[sR * 16384];

    // ---- phase 0: read m-frags 0-3 + all B-frags; issue A-stage; 16 MFMA
    bf16x8 af[4], bfv[4];
#pragma unroll
    for (int mf = 0; mf < 4; ++mf) af[mf]  = *(const bf16x8*)&As[aoffb + mf * 512];
#pragma unroll
    for (int nf = 0; nf < 4; ++nf) bfv[nf] = *(const bf16x8*)&As[boffb + nf * 512];
    STAGE_A(sW, kt);
    __builtin_amdgcn_s_barrier();
    __builtin_amdgcn_s_setprio(1);
#pragma unroll
    for (int mf = 0; mf < 4; ++mf)
#pragma unroll
      for (int nf = 0; nf < 4; ++nf)
        acc[mf][nf] = __builtin_amdgcn_mfma_f32_16x16x32_bf16(af[mf], bfv[nf], acc[mf][nf], 0, 0, 0);
    __builtin_amdgcn_s_setprio(0);
    __builtin_amdgcn_s_barrier();

    // ---- phase 1: read m-frags 4-7 (reuse B regs); issue B-stage; 16 MFMA
    bf16x8 ag[4];
#pragma unroll
    for (int mf = 0; mf < 4; ++mf) ag[mf] = *(const bf16x8*)&As[aoffb + (mf + 4) * 512];
    STAGE_B(sW, kt);
    __builtin_amdgcn_s_barrier();
    __builtin_amdgcn_s_setprio(1);
#pragma unroll
    for (int mf = 0; mf < 4; ++mf)
#pragma unroll
      for (int nf = 0; nf < 4; ++nf)
        acc[mf + 4][nf] = __builtin_amdgcn_mfma_f32_16x16x32_bf16(ag[mf], bfv[nf], acc[mf + 4][nf], 0, 0, 0);
    __builtin_amdgcn_s_setprio(0);
    // ---- K-tile boundary: ensure tile T+1 landed (newest 4 loads = tile T+2 stay in flight)
    asm volatile("s_waitcnt vmcnt(4)" ::: "memory");
    __builtin_amdgcn_s_barrier();

    sR = (sR == 2) ? 0 : sR + 1;
  }

  // ---- epilogue ----
  const int rowb = wm * 128;                 // wave row base within block
  if constexpr (MODE == 0) {
    // drain dead clamp-stage writes, then reuse LDS as [256][64] bf16 x3
    asm volatile("s_waitcnt vmcnt(0)" ::: "memory");
    __syncthreads();
    ushort* ldsD = lds;
    ushort* ldsU = lds + 16384;
    ushort* ldsG = lds + 32768;
    const int chl = wn * 16 + l15;           // channel within block's 64
    const int chg = bcol * 64 + chl;         // global channel
    const float ab = abase[chg];
#pragma unroll
    for (int mf = 0; mf < 8; ++mf) {
      const int rl0 = rowb + mf * 16 + lhi * 4;
#pragma unroll
      for (int r = 0; r < 4; ++r) {
        const float zd = acc[mf][0][r];
        const float zs = acc[mf][1][r];
        const float zi = acc[mf][2][r];
        const float zg = acc[mf][3][r];
        float sp = fmaxf(zd, 0.f) + log1pf(__expf(-fabsf(zd)));
        sp = fmaxf(sp, 1e-4f);
        const float dv = __expf(-sp * ab);
        const float sv = 1.f / (1.f + __expf(-zs));
        float tt = __expf(-2.f * fabsf(zi));
        float tv = (1.f - tt) / (1.f + tt);
        tv = (zi < 0.f) ? -tv : tv;
        const float gv = 1.f / (1.f + __expf(-zg));
        const int idx = (rl0 + r) * 64 + chl;
        ldsD[idx] = f2bf(dv);
        ldsU[idx] = f2bf(sv * tv);
        ldsG[idx] = f2bf(gv);
      }
    }
    __syncthreads();
    // coalesced stores: each row = 128B; 8 threads x 16B per row; 4 passes of 64 rows
    const int srow = t >> 3, schk = (t & 7) * 8;
    const size_t gbase = (size_t)(brow * 256) * D_ + bcol * 64 + schk;
#pragma unroll
    for (int it = 0; it < 4; ++it) {
      const int row = it * 64 + srow;
      const int lidx = row * 64 + schk;
      const size_t g = gbase + (size_t)row * D_;
      *(ushort8v*)&dec[g] = *(const ushort8v*)&ldsD[lidx];
      *(ushort8v*)&uu[g]  = *(const ushort8v*)&ldsU[lidx];
      *(ushort8v*)&gat[g] = *(const ushort8v*)&ldsG[lidx];
    }
  } else {
    const int colb = bcol * 256 + wn * 64;
#pragma unroll
    for (int mf = 0; mf < 8; ++mf) {
      const int rl0 = brow * 256 + rowb + mf * 16 + lhi * 4;
#pragma unroll
      for (int nf = 0; nf < 4; ++nf) {
        const int gc = colb + nf * 16 + l15;
#pragma unroll
        for (int r = 0; r < 4; ++r)
          outf[(size_t)(rl0 + r) * 1024 + gc] = acc[mf][nf][r];
      }
    }
  }
#undef STAGE_A
#undef STAGE_B
}

// ---------------- scan (3-phase chunked, exact affine composition) ----------------
__global__ __launch_bounds__(512) void k_scanA(
    const ushort* __restrict__ dec, const ushort* __restrict__ uu,
    float* __restrict__ cP, float* __restrict__ cL)
{
  const int t  = threadIdx.x;
  const int c  = blockIdx.x & (NCHUNK - 1);
  const int b  = blockIdx.x >> 7;
  const int e2 = t * 2;
  size_t base = ((size_t)b * S_ + (size_t)c * CHLEN) * D_ + e2;
  float P0 = 1.f, P1 = 1.f, L0 = 0.f, L1 = 0.f;
  for (int i = 0; i < CHLEN; ++i) {
    const uint dv = *(const uint*)(dec + base);
    const uint uv = *(const uint*)(uu + base);
    float d0 = bf2f(dv & 0xffffu), d1 = bf2f(dv >> 16);
    P0 *= d0; L0 = fmaf(d0, L0, bf2f(uv & 0xffffu));
    P1 *= d1; L1 = fmaf(d1, L1, bf2f(uv >> 16));
    base += D_;
  }
  size_t o = ((size_t)b * NCHUNK + c) * D_ + e2;
  cP[o] = P0; cP[o + 1] = P1; cL[o] = L0; cL[o + 1] = L1;
}

__global__ __launch_bounds__(512) void k_scanB(
    const float* __restrict__ cP, const float* __restrict__ cL, float* __restrict__ carry)
{
  const int idx = blockIdx.x * blockDim.x + threadIdx.x;  // 0..B_*D_-1
  const int b = idx >> 10, e = idx & 1023;
  float st = 0.f;
  size_t base = (size_t)b * NCHUNK * D_ + e;
  for (int c = 0; c < NCHUNK; ++c) {
    size_t o = base + (size_t)c * D_;
    carry[o] = st;
    st = fmaf(cP[o], st, cL[o]);
  }
}

__global__ __launch_bounds__(512) void k_scanC(
    const ushort* __restrict__ dec, const ushort* __restrict__ uu,
    const ushort* __restrict__ gat, const float* __restrict__ carry,
    ushort* __restrict__ outb)
{
  const int t  = threadIdx.x;
  const int c  = blockIdx.x & (NCHUNK - 1);
  const int b  = blockIdx.x >> 7;
  const int e2 = t * 2;
  size_t co = ((size_t)b * NCHUNK + c) * D_ + e2;
  float s0 = carry[co], s1 = carry[co + 1];
  size_t base = ((size_t)b * S_ + (size_t)c * CHLEN) * D_ + e2;
  for (int i = 0; i < CHLEN; ++i) {
    const uint dv = *(const uint*)(dec + base);
    const uint uv = *(const uint*)(uu + base);
    const uint gv = *(const uint*)(gat + base);
    s0 = fmaf(bf2f(dv & 0xffffu), s0, bf2f(uv & 0xffffu));
    s1 = fmaf(bf2f(dv >> 16),     s1, bf2f(uv >> 16));
    float o0 = bf2f(gv & 0xffffu) * s0;
    float o1 = bf2f(gv >> 16)     * s1;
    *(uint*)(outb + base) = (uint)f2bf(o0) | ((uint)f2bf(o1) << 16);
    base += D_;
  }
}

// ---------------- launcher ----------------
extern "C" void kernel_launch(void* const* d_in, const int* in_sizes, int n_in,
                              void* d_out, int out_size, void* d_ws, size_t ws_size,
                              hipStream_t stream) {
  const float* x     = (const float*)d_in[0];
  const float* W_in  = (const float*)d_in[1];
  const float* W_sel = (const float*)d_in[2];
  const float* W_gat = (const float*)d_in[3];
  const float* W_out = (const float*)d_in[4];
  const float* W_del = (const float*)d_in[5];
  const float* log_a = (const float*)d_in[6];
  float* y = (float*)d_out;

  char* ws = (char*)d_ws;
  size_t off = 0;
  auto alloc = [&](size_t bytes) { char* p = ws + off; off += (bytes + 255) & ~(size_t)255; return p; };
  ushort* xbf   = (ushort*)alloc((size_t)M_ * D_ * 2);   // reused as outb after GEMM0
  ushort* wcat  = (ushort*)alloc((size_t)NCAT * D_ * 2);
  ushort* woutb = (ushort*)alloc((size_t)D_ * D_ * 2);
  ushort* dec   = (ushort*)alloc((size_t)M_ * D_ * 2);
  ushort* uu    = (ushort*)alloc((size_t)M_ * D_ * 2);
  ushort* gat   = (ushort*)alloc((size_t)M_ * D_ * 2);
  float*  cP    = (float*)alloc((size_t)B_ * NCHUNK * D_ * 4);
  float*  cL    = (float*)alloc((size_t)B_ * NCHUNK * D_ * 4);
  float*  carry = (float*)alloc((size_t)B_ * NCHUNK * D_ * 4);
  float*  abase = (float*)alloc(D_ * 4);
  ushort* outb  = xbf;

  // K0: conversions
  k_cvt_f2b4<<<(M_ * D_ / 4 + 255) / 256, 256, 0, stream>>>(x, xbf, M_ * D_ / 4);
  k_build_wcat<<<(NCAT * D_ / 4 + 255) / 256, 256, 0, stream>>>(W_del, W_sel, W_in, W_gat, wcat);
  k_cvt_f2b4<<<(D_ * D_ / 4 + 255) / 256, 256, 0, stream>>>(W_out, woutb, D_ * D_ / 4);
  k_abase<<<(D_ + 255) / 256, 256, 0, stream>>>(log_a, abase);

  // K1: fused 4-projection GEMM + activation epilogue (interleaved Wcat)
  gemm8<0><<<(M_ / 256) * (NCAT / 256), 512, 0, stream>>>(
      xbf, wcat, NCAT / 256, nullptr, dec, uu, gat, abase);

  // K2: chunked scan
  k_scanA<<<B_ * NCHUNK, 512, 0, stream>>>(dec, uu, cP, cL);
  k_scanB<<<(B_ * D_) / 512, 512, 0, stream>>>(cP, cL, carry);
  k_scanC<<<B_ * NCHUNK, 512, 0, stream>>>(dec, uu, gat, carry, outb);

  // K3: output GEMM -> fp32 y
  gemm8<1><<<(M_ / 256) * (D_ / 256), 512, 0, stream>>>(
      outb, woutb, D_ / 256, y, nullptr, nullptr, nullptr, nullptr);
}

// Round 3
// 326.651 us; speedup vs baseline: 1.3459x; 1.0273x over previous
//
#include <hip/hip_runtime.h>
#include <hip/hip_bf16.h>
#include <math.h>

#define B_   4
#define S_   4096
#define D_   1024
#define M_   (B_*S_)        // 16384 rows
#define NCAT (4*D_)         // 4096 concat projection cols
#define KD   1024
#define NS   16             // K-steps of 64

#define NCHUNK 128          // scan chunks along S
#define CHLEN  (S_/NCHUNK)  // 32

typedef __bf16 bf16x8 __attribute__((ext_vector_type(8)));
typedef float  f32x4  __attribute__((ext_vector_type(4)));
typedef ushort ushort8v __attribute__((ext_vector_type(8)));

__device__ __forceinline__ ushort f2bf(float f) {
  union { float f; uint u; } v; v.f = f;
  uint u = v.u;
  return (ushort)((u + 0x7FFFu + ((u >> 16) & 1u)) >> 16);  // RNE
}
__device__ __forceinline__ float bf2f(uint bits16) {
  union { uint u; float f; } v; v.u = bits16 << 16;
  return v.f;
}

// global -> LDS direct (16B per lane). LDS dest linear: wave-uniform base + lane*16.
#define GLL(g, l) __builtin_amdgcn_global_load_lds( \
  (const __attribute__((address_space(1))) uint32_t*)(uintptr_t)(g), \
  (__attribute__((address_space(3))) uint32_t*)(uint32_t)(uintptr_t)(l), 16, 0, 0)

#define MFMA_(a, b, c) __builtin_amdgcn_mfma_f32_16x16x32_bf16(a, b, c, 0, 0, 0)

// ---------------- K0: conversions ----------------
__global__ void k_cvt_f2b4(const float* __restrict__ in, ushort* __restrict__ out, int n4) {
  int i = blockIdx.x * blockDim.x + threadIdx.x;
  if (i >= n4) return;
  const float4 v = ((const float4*)in)[i];
  uint2 o;
  o.x = (uint)f2bf(v.x) | ((uint)f2bf(v.y) << 16);
  o.y = (uint)f2bf(v.z) | ((uint)f2bf(v.w) << 16);
  ((uint2*)out)[i] = o;
}

// Interleaved Wcat: row n -> proj p=(n>>4)&3 of channel e=(n>>6)*16+(n&15)
__global__ void k_build_wcat(const float* __restrict__ wdel, const float* __restrict__ wsel,
                             const float* __restrict__ win,  const float* __restrict__ wgat,
                             ushort* __restrict__ wcat) {
  int i = blockIdx.x * blockDim.x + threadIdx.x;  // one per 4 elements
  int E = i * 4;
  int n   = E >> 10;
  int col = E & 1023;
  int p = (n >> 4) & 3;
  int e = ((n >> 6) << 4) + (n & 15);
  const float* src = (p == 0) ? wdel : (p == 1) ? wsel : (p == 2) ? win : wgat;
  const float4 v = *(const float4*)&src[(size_t)e * 1024 + col];
  uint2 o;
  o.x = (uint)f2bf(v.x) | ((uint)f2bf(v.y) << 16);
  o.y = (uint)f2bf(v.z) | ((uint)f2bf(v.w) << 16);
  *(uint2*)&wcat[E] = o;
}

__global__ void k_abase(const float* __restrict__ log_a, float* __restrict__ abase) {
  int i = blockIdx.x * blockDim.x + threadIdx.x;
  if (i < D_) abase[i] = 1.f / (1.f + __expf(-log_a[i]));
}

// ---------------- 256x256 GEMM, K-step 64, dbuf LDS, counted vmcnt, 4 phases/step ----
// C[m][n] = sum_k A[m][k]*B[n][k].
// LDS layout per buf (ushort idx): A: kk*8192 + r*32 + cp*8 ; B: 16384 + same.
// Swizzle: data chunk c stored at cp = c ^ (r&3); row stride 64B -> bank=(r&1,cp):
// fragment read (row=..+l15, c=lhi) hits 8 lanes per bank-group = conflict-free.
template<int MODE>
__global__ __launch_bounds__(512, 2) void gemm8p(
    const ushort* __restrict__ Ab, const ushort* __restrict__ Bb, int nbn,
    float* __restrict__ outf,
    ushort* __restrict__ dec, ushort* __restrict__ uu, ushort* __restrict__ gat,
    const float* __restrict__ abase)
{
  __shared__ ushort lds[65536];  // 128 KB: 2 bufs x (A 32KB + B 32KB)

  const int nwg = gridDim.x;
  const int bid = blockIdx.x;
  const int nb  = (bid & 7) * (nwg >> 3) + (bid >> 3);   // XCD-bijective (nwg%8==0)
  const int brow = nb / nbn, bcol = nb % nbn;
  const int t = threadIdx.x, lane = t & 63, w = t >> 6;
  const int wm = w >> 2, wn = w & 3;
  const int l15 = lane & 15, lhi = lane >> 4, l3 = lane & 3;

  // ---- staging: thread covers 16B chunks h0,h1 of each 1024-chunk (16KB) unit
  const int h0 = w * 128 + lane, h1 = h0 + 64;
  const int r0 = h0 >> 2, cg0 = (h0 & 3) ^ (r0 & 3);
  const int r1 = h1 >> 2, cg1 = (h1 & 3) ^ (r1 & 3);
  const ushort* aS0 = Ab + (size_t)(brow * 256 + r0) * KD + cg0 * 8;
  const ushort* aS1 = Ab + (size_t)(brow * 256 + r1) * KD + cg1 * 8;
  const ushort* bS0 = Bb + (size_t)(bcol * 256 + r0) * KD + cg0 * 8;
  const ushort* bS1 = Bb + (size_t)(bcol * 256 + r1) * KD + cg1 * 8;
  const int dA0 = h0 * 8, dA1 = h1 * 8;
  const int dB0 = 16384 + h0 * 8, dB1 = 16384 + h1 * 8;

#define STG_A(SB, KK, KO) do { \
    GLL(aS0 + (KO) + (KK) * 32, &lds[(SB) * 32768 + (KK) * 8192 + dA0]); \
    GLL(aS1 + (KO) + (KK) * 32, &lds[(SB) * 32768 + (KK) * 8192 + dA1]); } while (0)
#define STG_B(SB, KK, KO) do { \
    GLL(bS0 + (KO) + (KK) * 32, &lds[(SB) * 32768 + (KK) * 8192 + dB0]); \
    GLL(bS1 + (KO) + (KK) * 32, &lds[(SB) * 32768 + (KK) * 8192 + dB1]); } while (0)

  // ---- fragment read bases (swizzled)
  const int swp = (lhi ^ l3) * 8;
  const ushort* fA = &lds[(wm * 128 + l15) * 32 + swp];          // +BUF*32768 +kk*8192 +mf*512
  const ushort* fB = &lds[16384 + (wn * 64 + l15) * 32 + swp];   // +BUF*32768 +kk*8192 +nf*512

  f32x4 acc[8][4] = {};

// one K-step: 4 phases {kk,nh}; reads buf BUF, stages step at KO into buf SB.
// vmcnt(4)+barrier before phases 0 and 2 guarantee exactly the units those phases read.
#define KSTEP(BUF, SB, KO) do { \
    asm volatile("s_waitcnt vmcnt(4)" ::: "memory"); \
    __builtin_amdgcn_s_barrier(); \
    bf16x8 a0[8], bA, bB; \
    _Pragma("unroll") \
    for (int mf = 0; mf < 8; ++mf) a0[mf] = *(const bf16x8*)&fA[(BUF) * 32768 + mf * 512]; \
    bA = *(const bf16x8*)&fB[(BUF) * 32768 + 0 * 512]; \
    bB = *(const bf16x8*)&fB[(BUF) * 32768 + 1 * 512]; \
    STG_A(SB, 0, KO); \
    __builtin_amdgcn_s_setprio(1); \
    _Pragma("unroll") \
    for (int mf = 0; mf < 8; ++mf) { \
      acc[mf][0] = MFMA_(a0[mf], bA, acc[mf][0]); \
      acc[mf][1] = MFMA_(a0[mf], bB, acc[mf][1]); } \
    __builtin_amdgcn_s_setprio(0); \
    __builtin_amdgcn_s_barrier(); \
    bA = *(const bf16x8*)&fB[(BUF) * 32768 + 2 * 512]; \
    bB = *(const bf16x8*)&fB[(BUF) * 32768 + 3 * 512]; \
    STG_B(SB, 0, KO); \
    __builtin_amdgcn_s_setprio(1); \
    _Pragma("unroll") \
    for (int mf = 0; mf < 8; ++mf) { \
      acc[mf][2] = MFMA_(a0[mf], bA, acc[mf][2]); \
      acc[mf][3] = MFMA_(a0[mf], bB, acc[mf][3]); } \
    __builtin_amdgcn_s_setprio(0); \
    asm volatile("s_waitcnt vmcnt(4)" ::: "memory"); \
    __builtin_amdgcn_s_barrier(); \
    _Pragma("unroll") \
    for (int mf = 0; mf < 8; ++mf) a0[mf] = *(const bf16x8*)&fA[(BUF) * 32768 + 8192 + mf * 512]; \
    bA = *(const bf16x8*)&fB[(BUF) * 32768 + 8192 + 0 * 512]; \
    bB = *(const bf16x8*)&fB[(BUF) * 32768 + 8192 + 1 * 512]; \
    STG_A(SB, 1, KO); \
    __builtin_amdgcn_s_setprio(1); \
    _Pragma("unroll") \
    for (int mf = 0; mf < 8; ++mf) { \
      acc[mf][0] = MFMA_(a0[mf], bA, acc[mf][0]); \
      acc[mf][1] = MFMA_(a0[mf], bB, acc[mf][1]); } \
    __builtin_amdgcn_s_setprio(0); \
    __builtin_amdgcn_s_barrier(); \
    bA = *(const bf16x8*)&fB[(BUF) * 32768 + 8192 + 2 * 512]; \
    bB = *(const bf16x8*)&fB[(BUF) * 32768 + 8192 + 3 * 512]; \
    STG_B(SB, 1, KO); \
    __builtin_amdgcn_s_setprio(1); \
    _Pragma("unroll") \
    for (int mf = 0; mf < 8; ++mf) { \
      acc[mf][2] = MFMA_(a0[mf], bA, acc[mf][2]); \
      acc[mf][3] = MFMA_(a0[mf], bB, acc[mf][3]); } \
    __builtin_amdgcn_s_setprio(0); \
  } while (0)

  // prologue: stage step 0 into buf0 (order A0,B0,A1,B1 for vmcnt accounting)
  STG_A(0, 0, 0); STG_B(0, 0, 0); STG_A(0, 1, 0); STG_B(0, 1, 0);

  for (int it = 0; it < 8; ++it) {
    const int k1 = it * 128 + 64;
    const int k2 = (it == 7) ? 960 : it * 128 + 128;  // tail: dead re-stage of step 15
    KSTEP(0, 1, k1);
    KSTEP(1, 0, k2);
  }

  asm volatile("s_waitcnt vmcnt(0)" ::: "memory");
  __syncthreads();

  // ---- epilogue ----
  const int rowb = wm * 128;
  if constexpr (MODE == 0) {
    // reuse LDS as [256][64] bf16 x3 (dec/u/gate), then coalesced 16B stores
    ushort* ldsD = lds;
    ushort* ldsU = lds + 16384;
    ushort* ldsG = lds + 32768;
    const int chl = wn * 16 + l15;           // channel within block's 64
    const int chg = bcol * 64 + chl;         // global channel
    const float ab = abase[chg];
#pragma unroll
    for (int mf = 0; mf < 8; ++mf) {
      const int rl0 = rowb + mf * 16 + lhi * 4;
#pragma unroll
      for (int r = 0; r < 4; ++r) {
        const float zd = acc[mf][0][r];
        const float zs = acc[mf][1][r];
        const float zi = acc[mf][2][r];
        const float zg = acc[mf][3][r];
        float sp = fmaxf(zd, 0.f) + log1pf(__expf(-fabsf(zd)));
        sp = fmaxf(sp, 1e-4f);
        const float dv = __expf(-sp * ab);
        const float sv = 1.f / (1.f + __expf(-zs));
        float tt = __expf(-2.f * fabsf(zi));
        float tv = (1.f - tt) / (1.f + tt);
        tv = (zi < 0.f) ? -tv : tv;
        const float gv = 1.f / (1.f + __expf(-zg));
        const int idx = (rl0 + r) * 64 + chl;
        ldsD[idx] = f2bf(dv);
        ldsU[idx] = f2bf(sv * tv);
        ldsG[idx] = f2bf(gv);
      }
    }
    __syncthreads();
    const int srow = t >> 3, schk = (t & 7) * 8;
    const size_t gbase = (size_t)(brow * 256) * D_ + bcol * 64 + schk;
#pragma unroll
    for (int itp = 0; itp < 4; ++itp) {
      const int row = itp * 64 + srow;
      const int lidx = row * 64 + schk;
      const size_t g = gbase + (size_t)row * D_;
      *(ushort8v*)&dec[g] = *(const ushort8v*)&ldsD[lidx];
      *(ushort8v*)&uu[g]  = *(const ushort8v*)&ldsU[lidx];
      *(ushort8v*)&gat[g] = *(const ushort8v*)&ldsG[lidx];
    }
  } else {
    const int colb = bcol * 256 + wn * 64;
#pragma unroll
    for (int mf = 0; mf < 8; ++mf) {
      const int rl0 = brow * 256 + rowb + mf * 16 + lhi * 4;
#pragma unroll
      for (int nf = 0; nf < 4; ++nf) {
        const int gc = colb + nf * 16 + l15;
#pragma unroll
        for (int r = 0; r < 4; ++r)
          outf[(size_t)(rl0 + r) * 1024 + gc] = acc[mf][nf][r];
      }
    }
  }
#undef KSTEP
#undef STG_A
#undef STG_B
}

// ---------------- scan (3-phase chunked, exact affine composition) ----------------
__global__ __launch_bounds__(512) void k_scanA(
    const ushort* __restrict__ dec, const ushort* __restrict__ uu,
    float* __restrict__ cP, float* __restrict__ cL)
{
  const int t  = threadIdx.x;
  const int c  = blockIdx.x & (NCHUNK - 1);
  const int b  = blockIdx.x >> 7;
  const int e2 = t * 2;
  size_t base = ((size_t)b * S_ + (size_t)c * CHLEN) * D_ + e2;
  float P0 = 1.f, P1 = 1.f, L0 = 0.f, L1 = 0.f;
  for (int i = 0; i < CHLEN; ++i) {
    const uint dv = *(const uint*)(dec + base);
    const uint uv = *(const uint*)(uu + base);
    float d0 = bf2f(dv & 0xffffu), d1 = bf2f(dv >> 16);
    P0 *= d0; L0 = fmaf(d0, L0, bf2f(uv & 0xffffu));
    P1 *= d1; L1 = fmaf(d1, L1, bf2f(uv >> 16));
    base += D_;
  }
  size_t o = ((size_t)b * NCHUNK + c) * D_ + e2;
  cP[o] = P0; cP[o + 1] = P1; cL[o] = L0; cL[o + 1] = L1;
}

__global__ __launch_bounds__(64) void k_scanB(
    const float* __restrict__ cP, const float* __restrict__ cL, float* __restrict__ carry)
{
  const int idx = blockIdx.x * 64 + threadIdx.x;  // 0..B_*D_-1
  const int b = idx >> 10, e = idx & 1023;
  float st = 0.f;
  size_t base = (size_t)b * NCHUNK * D_ + e;
  for (int c = 0; c < NCHUNK; ++c) {
    size_t o = base + (size_t)c * D_;
    carry[o] = st;
    st = fmaf(cP[o], st, cL[o]);
  }
}

__global__ __launch_bounds__(512) void k_scanC(
    const ushort* __restrict__ dec, const ushort* __restrict__ uu,
    const ushort* __restrict__ gat, const float* __restrict__ carry,
    ushort* __restrict__ outb)
{
  const int t  = threadIdx.x;
  const int c  = blockIdx.x & (NCHUNK - 1);
  const int b  = blockIdx.x >> 7;
  const int e2 = t * 2;
  size_t co = ((size_t)b * NCHUNK + c) * D_ + e2;
  float s0 = carry[co], s1 = carry[co + 1];
  size_t base = ((size_t)b * S_ + (size_t)c * CHLEN) * D_ + e2;
  for (int i = 0; i < CHLEN; ++i) {
    const uint dv = *(const uint*)(dec + base);
    const uint uv = *(const uint*)(uu + base);
    const uint gv = *(const uint*)(gat + base);
    s0 = fmaf(bf2f(dv & 0xffffu), s0, bf2f(uv & 0xffffu));
    s1 = fmaf(bf2f(dv >> 16),     s1, bf2f(uv >> 16));
    float o0 = bf2f(gv & 0xffffu) * s0;
    float o1 = bf2f(gv >> 16)     * s1;
    *(uint*)(outb + base) = (uint)f2bf(o0) | ((uint)f2bf(o1) << 16);
    base += D_;
  }
}

// ---------------- launcher ----------------
extern "C" void kernel_launch(void* const* d_in, const int* in_sizes, int n_in,
                              void* d_out, int out_size, void* d_ws, size_t ws_size,
                              hipStream_t stream) {
  const float* x     = (const float*)d_in[0];
  const float* W_in  = (const float*)d_in[1];
  const float* W_sel = (const float*)d_in[2];
  const float* W_gat = (const float*)d_in[3];
  const float* W_out = (const float*)d_in[4];
  const float* W_del = (const float*)d_in[5];
  const float* log_a = (const float*)d_in[6];
  float* y = (float*)d_out;

  char* ws = (char*)d_ws;
  size_t off = 0;
  auto alloc = [&](size_t bytes) { char* p = ws + off; off += (bytes + 255) & ~(size_t)255; return p; };
  ushort* xbf   = (ushort*)alloc((size_t)M_ * D_ * 2);   // reused as outb after GEMM0
  ushort* wcat  = (ushort*)alloc((size_t)NCAT * D_ * 2);
  ushort* woutb = (ushort*)alloc((size_t)D_ * D_ * 2);
  ushort* dec   = (ushort*)alloc((size_t)M_ * D_ * 2);
  ushort* uu    = (ushort*)alloc((size_t)M_ * D_ * 2);
  ushort* gat   = (ushort*)alloc((size_t)M_ * D_ * 2);
  float*  cP    = (float*)alloc((size_t)B_ * NCHUNK * D_ * 4);
  float*  cL    = (float*)alloc((size_t)B_ * NCHUNK * D_ * 4);
  float*  carry = (float*)alloc((size_t)B_ * NCHUNK * D_ * 4);
  float*  abase = (float*)alloc(D_ * 4);
  ushort* outb  = xbf;

  // K0: conversions
  k_cvt_f2b4<<<(M_ * D_ / 4 + 255) / 256, 256, 0, stream>>>(x, xbf, M_ * D_ / 4);
  k_build_wcat<<<(NCAT * D_ / 4 + 255) / 256, 256, 0, stream>>>(W_del, W_sel, W_in, W_gat, wcat);
  k_cvt_f2b4<<<(D_ * D_ / 4 + 255) / 256, 256, 0, stream>>>(W_out, woutb, D_ * D_ / 4);
  k_abase<<<(D_ + 255) / 256, 256, 0, stream>>>(log_a, abase);

  // K1: fused 4-projection GEMM + activation epilogue (interleaved Wcat)
  gemm8p<0><<<(M_ / 256) * (NCAT / 256), 512, 0, stream>>>(
      xbf, wcat, NCAT / 256, nullptr, dec, uu, gat, abase);

  // K2: chunked scan
  k_scanA<<<B_ * NCHUNK, 512, 0, stream>>>(dec, uu, cP, cL);
  k_scanB<<<(B_ * D_) / 64, 64, 0, stream>>>(cP, cL, carry);
  k_scanC<<<B_ * NCHUNK, 512, 0, stream>>>(dec, uu, gat, carry, outb);

  // K3: output GEMM -> fp32 y
  gemm8p<1><<<(M_ / 256) * (D_ / 256), 512, 0, stream>>>(
      outb, woutb, D_ / 256, y, nullptr, nullptr, nullptr, nullptr);
}

// Round 4
// 323.364 us; speedup vs baseline: 1.3596x; 1.0102x over previous
//
#include <hip/hip_runtime.h>
#include <hip/hip_bf16.h>
#include <math.h>

#define B_   4
#define S_   4096
#define D_   1024
#define M_   (B_*S_)        // 16384 rows
#define NCAT (4*D_)         // 4096 concat projection cols
#define KD   1024

#define NCHUNK 128          // scan chunks along S
#define CHLEN  (S_/NCHUNK)  // 32

typedef __bf16 bf16x8 __attribute__((ext_vector_type(8)));
typedef float  f32x4  __attribute__((ext_vector_type(4)));
typedef ushort ushort8v __attribute__((ext_vector_type(8)));

__device__ __forceinline__ ushort f2bf(float f) {
  union { float f; uint u; } v; v.f = f;
  uint u = v.u;
  return (ushort)((u + 0x7FFFu + ((u >> 16) & 1u)) >> 16);  // RNE
}
__device__ __forceinline__ float bf2f(uint bits16) {
  union { uint u; float f; } v; v.u = bits16 << 16;
  return v.f;
}

// global -> LDS direct (16B per lane). LDS dest linear: wave-uniform base + lane*16.
#define GLL(g, l) __builtin_amdgcn_global_load_lds( \
  (const __attribute__((address_space(1))) uint32_t*)(uintptr_t)(g), \
  (__attribute__((address_space(3))) uint32_t*)(uint32_t)(uintptr_t)(l), 16, 0, 0)

#define MFMA_(a, b, c) __builtin_amdgcn_mfma_f32_16x16x32_bf16(a, b, c, 0, 0, 0)

// ---------------- K0: conversions ----------------
__global__ void k_cvt_f2b4(const float* __restrict__ in, ushort* __restrict__ out, int n4) {
  int i = blockIdx.x * blockDim.x + threadIdx.x;
  if (i >= n4) return;
  const float4 v = ((const float4*)in)[i];
  uint2 o;
  o.x = (uint)f2bf(v.x) | ((uint)f2bf(v.y) << 16);
  o.y = (uint)f2bf(v.z) | ((uint)f2bf(v.w) << 16);
  ((uint2*)out)[i] = o;
}

// Interleaved Wcat: row n -> proj p=(n>>4)&3 of channel e=(n>>6)*16+(n&15)
__global__ void k_build_wcat(const float* __restrict__ wdel, const float* __restrict__ wsel,
                             const float* __restrict__ win,  const float* __restrict__ wgat,
                             ushort* __restrict__ wcat) {
  int i = blockIdx.x * blockDim.x + threadIdx.x;  // one per 4 elements
  int E = i * 4;
  int n   = E >> 10;
  int col = E & 1023;
  int p = (n >> 4) & 3;
  int e = ((n >> 6) << 4) + (n & 15);
  const float* src = (p == 0) ? wdel : (p == 1) ? wsel : (p == 2) ? win : wgat;
  const float4 v = *(const float4*)&src[(size_t)e * 1024 + col];
  uint2 o;
  o.x = (uint)f2bf(v.x) | ((uint)f2bf(v.y) << 16);
  o.y = (uint)f2bf(v.z) | ((uint)f2bf(v.w) << 16);
  *(uint2*)&wcat[E] = o;
}

__global__ void k_abase(const float* __restrict__ log_a, float* __restrict__ abase) {
  int i = blockIdx.x * blockDim.x + threadIdx.x;
  if (i < D_) abase[i] = 1.f / (1.f + __expf(-log_a[i]));
}

// ---------------- 256x256 GEMM, K-step 64, dbuf LDS, counted vmcnt, 4 phases/step ----
// C[m][n] = sum_k A[m][k]*B[n][k].
// LDS per buf (ushort idx): A: kk*8192 + r*32 + s*8 ; B: 16384 + same.
// Swizzle (verified R2): data chunk c of row r stored at s = c ^ ((r>>1)&3).
// Bank group = 16*(r&1) + 4*s -> every aligned 8-lane phase of a b128 read hits
// 8 distinct groups (conflict-free).
template<int MODE>
__global__ __launch_bounds__(512, 2) void gemm8p(
    const ushort* __restrict__ Ab, const ushort* __restrict__ Bb, int nbn,
    float* __restrict__ outf,
    ushort* __restrict__ dec, ushort* __restrict__ uu, ushort* __restrict__ gat,
    const float* __restrict__ abase)
{
  __shared__ ushort lds[65536];  // 128 KB: 2 bufs x (A 32KB + B 32KB)

  const int nwg = gridDim.x;
  const int bid = blockIdx.x;
  const int nb  = (bid & 7) * (nwg >> 3) + (bid >> 3);   // XCD-bijective (nwg%8==0)
  const int brow = nb / nbn, bcol = nb % nbn;
  const int t = threadIdx.x, lane = t & 63, w = t >> 6;
  const int wm = w >> 2, wn = w & 3;
  const int l15 = lane & 15, lhi = lane >> 4;

  // ---- staging: thread covers 16B chunks h0,h1 of each 1024-chunk (16KB) unit
  const int h0 = w * 128 + lane, h1 = h0 + 64;
  const int r0 = h0 >> 2, cg0 = (h0 & 3) ^ ((r0 >> 1) & 3);
  const int r1 = h1 >> 2, cg1 = (h1 & 3) ^ ((r1 >> 1) & 3);
  const ushort* aS0 = Ab + (size_t)(brow * 256 + r0) * KD + cg0 * 8;
  const ushort* aS1 = Ab + (size_t)(brow * 256 + r1) * KD + cg1 * 8;
  const ushort* bS0 = Bb + (size_t)(bcol * 256 + r0) * KD + cg0 * 8;
  const ushort* bS1 = Bb + (size_t)(bcol * 256 + r1) * KD + cg1 * 8;
  const int dA0 = h0 * 8, dA1 = h1 * 8;
  const int dB0 = 16384 + h0 * 8, dB1 = 16384 + h1 * 8;

#define STG_A(SB, KK, KO) do { \
    GLL(aS0 + (KO) + (KK) * 32, &lds[(SB) * 32768 + (KK) * 8192 + dA0]); \
    GLL(aS1 + (KO) + (KK) * 32, &lds[(SB) * 32768 + (KK) * 8192 + dA1]); } while (0)
#define STG_B(SB, KK, KO) do { \
    GLL(bS0 + (KO) + (KK) * 32, &lds[(SB) * 32768 + (KK) * 8192 + dB0]); \
    GLL(bS1 + (KO) + (KK) * 32, &lds[(SB) * 32768 + (KK) * 8192 + dB1]); } while (0)

  // ---- fragment read bases (swizzled): want chunk lhi of row (..+l15)
  const int swp = (lhi ^ ((l15 >> 1) & 3)) * 8;
  const ushort* fA = &lds[(wm * 128 + l15) * 32 + swp];          // +BUF*32768 +kk*8192 +mf*512
  const ushort* fB = &lds[16384 + (wn * 64 + l15) * 32 + swp];   // +BUF*32768 +kk*8192 +nf*512

  f32x4 acc[8][4] = {};

// one K-step: 4 phases; reads buf BUF, stages step at KO into buf SB.
// vmcnt(4)+barrier before phases 0 and 2 guarantee exactly the units those phases read.
#define KSTEP(BUF, SB, KO) do { \
    asm volatile("s_waitcnt vmcnt(4)" ::: "memory"); \
    __builtin_amdgcn_s_barrier(); \
    bf16x8 a0[8], bA, bB; \
    _Pragma("unroll") \
    for (int mf = 0; mf < 8; ++mf) a0[mf] = *(const bf16x8*)&fA[(BUF) * 32768 + mf * 512]; \
    bA = *(const bf16x8*)&fB[(BUF) * 32768 + 0 * 512]; \
    bB = *(const bf16x8*)&fB[(BUF) * 32768 + 1 * 512]; \
    STG_A(SB, 0, KO); \
    __builtin_amdgcn_s_setprio(1); \
    _Pragma("unroll") \
    for (int mf = 0; mf < 8; ++mf) { \
      acc[mf][0] = MFMA_(a0[mf], bA, acc[mf][0]); \
      acc[mf][1] = MFMA_(a0[mf], bB, acc[mf][1]); } \
    __builtin_amdgcn_s_setprio(0); \
    __builtin_amdgcn_s_barrier(); \
    bA = *(const bf16x8*)&fB[(BUF) * 32768 + 2 * 512]; \
    bB = *(const bf16x8*)&fB[(BUF) * 32768 + 3 * 512]; \
    STG_B(SB, 0, KO); \
    __builtin_amdgcn_s_setprio(1); \
    _Pragma("unroll") \
    for (int mf = 0; mf < 8; ++mf) { \
      acc[mf][2] = MFMA_(a0[mf], bA, acc[mf][2]); \
      acc[mf][3] = MFMA_(a0[mf], bB, acc[mf][3]); } \
    __builtin_amdgcn_s_setprio(0); \
    asm volatile("s_waitcnt vmcnt(4)" ::: "memory"); \
    __builtin_amdgcn_s_barrier(); \
    _Pragma("unroll") \
    for (int mf = 0; mf < 8; ++mf) a0[mf] = *(const bf16x8*)&fA[(BUF) * 32768 + 8192 + mf * 512]; \
    bA = *(const bf16x8*)&fB[(BUF) * 32768 + 8192 + 0 * 512]; \
    bB = *(const bf16x8*)&fB[(BUF) * 32768 + 8192 + 1 * 512]; \
    STG_A(SB, 1, KO); \
    __builtin_amdgcn_s_setprio(1); \
    _Pragma("unroll") \
    for (int mf = 0; mf < 8; ++mf) { \
      acc[mf][0] = MFMA_(a0[mf], bA, acc[mf][0]); \
      acc[mf][1] = MFMA_(a0[mf], bB, acc[mf][1]); } \
    __builtin_amdgcn_s_setprio(0); \
    __builtin_amdgcn_s_barrier(); \
    bA = *(const bf16x8*)&fB[(BUF) * 32768 + 8192 + 2 * 512]; \
    bB = *(const bf16x8*)&fB[(BUF) * 32768 + 8192 + 3 * 512]; \
    STG_B(SB, 1, KO); \
    __builtin_amdgcn_s_setprio(1); \
    _Pragma("unroll") \
    for (int mf = 0; mf < 8; ++mf) { \
      acc[mf][2] = MFMA_(a0[mf], bA, acc[mf][2]); \
      acc[mf][3] = MFMA_(a0[mf], bB, acc[mf][3]); } \
    __builtin_amdgcn_s_setprio(0); \
  } while (0)

  // prologue: stage step 0 into buf0 (order A0,B0,A1,B1 for vmcnt accounting)
  STG_A(0, 0, 0); STG_B(0, 0, 0); STG_A(0, 1, 0); STG_B(0, 1, 0);

  for (int it = 0; it < 8; ++it) {
    const int k1 = it * 128 + 64;
    const int k2 = (it == 7) ? 960 : it * 128 + 128;  // tail: dead re-stage of step 15
    KSTEP(0, 1, k1);
    KSTEP(1, 0, k2);
  }

  asm volatile("s_waitcnt vmcnt(0)" ::: "memory");
  __syncthreads();

  // ---- epilogue ----
  const int rowb = wm * 128;
  if constexpr (MODE == 0) {
    // reuse LDS as [256][64] bf16 x3 (dec/u/gate), XOR-swizzled 8-ushort chunks
    ushort* ldsD = lds;
    ushort* ldsU = lds + 16384;
    ushort* ldsG = lds + 32768;
    const int chl = wn * 16 + l15;           // channel within block's 64
    const int chg = bcol * 64 + chl;         // global channel
    const float ab = abase[chg];
#pragma unroll
    for (int mf = 0; mf < 8; ++mf) {
      const int rl0 = rowb + mf * 16 + lhi * 4;
#pragma unroll
      for (int r = 0; r < 4; ++r) {
        const float zd = acc[mf][0][r];
        const float zs = acc[mf][1][r];
        const float zi = acc[mf][2][r];
        const float zg = acc[mf][3][r];
        float sp = fmaxf(zd, 0.f) + log1pf(__expf(-fabsf(zd)));
        sp = fmaxf(sp, 1e-4f);
        const float dv = __expf(-sp * ab);
        const float sv = 1.f / (1.f + __expf(-zs));
        float tt = __expf(-2.f * fabsf(zi));
        float tv = (1.f - tt) / (1.f + tt);
        tv = (zi < 0.f) ? -tv : tv;
        const float gv = 1.f / (1.f + __expf(-zg));
        const int row = rl0 + r;
        const int idx = row * 64 + ((((chl >> 3) ^ (row & 7)) << 3) | (chl & 7));
        ldsD[idx] = f2bf(dv);
        ldsU[idx] = f2bf(sv * tv);
        ldsG[idx] = f2bf(gv);
      }
    }
    __syncthreads();
    const int srow = t >> 3, cD = t & 7;
    const size_t gbase = (size_t)(brow * 256) * D_ + bcol * 64 + cD * 8;
#pragma unroll
    for (int itp = 0; itp < 4; ++itp) {
      const int row = itp * 64 + srow;
      const int lidx = row * 64 + ((cD ^ (row & 7)) << 3);
      const size_t g = gbase + (size_t)row * D_;
      *(ushort8v*)&dec[g] = *(const ushort8v*)&ldsD[lidx];
      *(ushort8v*)&uu[g]  = *(const ushort8v*)&ldsU[lidx];
      *(ushort8v*)&gat[g] = *(const ushort8v*)&ldsG[lidx];
    }
  } else {
    const int colb = bcol * 256 + wn * 64;
#pragma unroll
    for (int mf = 0; mf < 8; ++mf) {
      const int rl0 = brow * 256 + rowb + mf * 16 + lhi * 4;
#pragma unroll
      for (int nf = 0; nf < 4; ++nf) {
        const int gc = colb + nf * 16 + l15;
#pragma unroll
        for (int r = 0; r < 4; ++r)
          outf[(size_t)(rl0 + r) * 1024 + gc] = acc[mf][nf][r];
      }
    }
  }
#undef KSTEP
#undef STG_A
#undef STG_B
}

// ---------------- scan (3-phase chunked, exact affine composition) ----------------
__global__ __launch_bounds__(512) void k_scanA(
    const ushort* __restrict__ dec, const ushort* __restrict__ uu,
    float* __restrict__ cP, float* __restrict__ cL)
{
  const int t  = threadIdx.x;
  const int c  = blockIdx.x & (NCHUNK - 1);
  const int b  = blockIdx.x >> 7;
  const int e2 = t * 2;
  size_t base = ((size_t)b * S_ + (size_t)c * CHLEN) * D_ + e2;
  float P0 = 1.f, P1 = 1.f, L0 = 0.f, L1 = 0.f;
  for (int i = 0; i < CHLEN; ++i) {
    const uint dv = *(const uint*)(dec + base);
    const uint uv = *(const uint*)(uu + base);
    float d0 = bf2f(dv & 0xffffu), d1 = bf2f(dv >> 16);
    P0 *= d0; L0 = fmaf(d0, L0, bf2f(uv & 0xffffu));
    P1 *= d1; L1 = fmaf(d1, L1, bf2f(uv >> 16));
    base += D_;
  }
  size_t o = ((size_t)b * NCHUNK + c) * D_ + e2;
  cP[o] = P0; cP[o + 1] = P1; cL[o] = L0; cL[o + 1] = L1;
}

__global__ __launch_bounds__(64) void k_scanB(
    const float* __restrict__ cP, const float* __restrict__ cL, float* __restrict__ carry)
{
  const int idx = blockIdx.x * 64 + threadIdx.x;  // 0..B_*D_-1
  const int b = idx >> 10, e = idx & 1023;
  float st = 0.f;
  size_t base = (size_t)b * NCHUNK * D_ + e;
  for (int c = 0; c < NCHUNK; ++c) {
    size_t o = base + (size_t)c * D_;
    carry[o] = st;
    st = fmaf(cP[o], st, cL[o]);
  }
}

__global__ __launch_bounds__(512) void k_scanC(
    const ushort* __restrict__ dec, const ushort* __restrict__ uu,
    const ushort* __restrict__ gat, const float* __restrict__ carry,
    ushort* __restrict__ outb)
{
  const int t  = threadIdx.x;
  const int c  = blockIdx.x & (NCHUNK - 1);
  const int b  = blockIdx.x >> 7;
  const int e2 = t * 2;
  size_t co = ((size_t)b * NCHUNK + c) * D_ + e2;
  float s0 = carry[co], s1 = carry[co + 1];
  size_t base = ((size_t)b * S_ + (size_t)c * CHLEN) * D_ + e2;
  for (int i = 0; i < CHLEN; ++i) {
    const uint dv = *(const uint*)(dec + base);
    const uint uv = *(const uint*)(uu + base);
    const uint gv = *(const uint*)(gat + base);
    s0 = fmaf(bf2f(dv & 0xffffu), s0, bf2f(uv & 0xffffu));
    s1 = fmaf(bf2f(dv >> 16),     s1, bf2f(uv >> 16));
    float o0 = bf2f(gv & 0xffffu) * s0;
    float o1 = bf2f(gv >> 16)     * s1;
    *(uint*)(outb + base) = (uint)f2bf(o0) | ((uint)f2bf(o1) << 16);
    base += D_;
  }
}

// ---------------- launcher ----------------
extern "C" void kernel_launch(void* const* d_in, const int* in_sizes, int n_in,
                              void* d_out, int out_size, void* d_ws, size_t ws_size,
                              hipStream_t stream) {
  const float* x     = (const float*)d_in[0];
  const float* W_in  = (const float*)d_in[1];
  const float* W_sel = (const float*)d_in[2];
  const float* W_gat = (const float*)d_in[3];
  const float* W_out = (const float*)d_in[4];
  const float* W_del = (const float*)d_in[5];
  const float* log_a = (const float*)d_in[6];
  float* y = (float*)d_out;

  char* ws = (char*)d_ws;
  size_t off = 0;
  auto alloc = [&](size_t bytes) { char* p = ws + off; off += (bytes + 255) & ~(size_t)255; return p; };
  ushort* xbf   = (ushort*)alloc((size_t)M_ * D_ * 2);   // reused as outb after GEMM0
  ushort* wcat  = (ushort*)alloc((size_t)NCAT * D_ * 2);
  ushort* woutb = (ushort*)alloc((size_t)D_ * D_ * 2);
  ushort* dec   = (ushort*)alloc((size_t)M_ * D_ * 2);
  ushort* uu    = (ushort*)alloc((size_t)M_ * D_ * 2);
  ushort* gat   = (ushort*)alloc((size_t)M_ * D_ * 2);
  float*  cP    = (float*)alloc((size_t)B_ * NCHUNK * D_ * 4);
  float*  cL    = (float*)alloc((size_t)B_ * NCHUNK * D_ * 4);
  float*  carry = (float*)alloc((size_t)B_ * NCHUNK * D_ * 4);
  float*  abase = (float*)alloc(D_ * 4);
  ushort* outb  = xbf;

  // K0: conversions
  k_cvt_f2b4<<<(M_ * D_ / 4 + 255) / 256, 256, 0, stream>>>(x, xbf, M_ * D_ / 4);
  k_build_wcat<<<(NCAT * D_ / 4 + 255) / 256, 256, 0, stream>>>(W_del, W_sel, W_in, W_gat, wcat);
  k_cvt_f2b4<<<(D_ * D_ / 4 + 255) / 256, 256, 0, stream>>>(W_out, woutb, D_ * D_ / 4);
  k_abase<<<(D_ + 255) / 256, 256, 0, stream>>>(log_a, abase);

  // K1: fused 4-projection GEMM + activation epilogue (interleaved Wcat)
  gemm8p<0><<<(M_ / 256) * (NCAT / 256), 512, 0, stream>>>(
      xbf, wcat, NCAT / 256, nullptr, dec, uu, gat, abase);

  // K2: chunked scan
  k_scanA<<<B_ * NCHUNK, 512, 0, stream>>>(dec, uu, cP, cL);
  k_scanB<<<(B_ * D_) / 64, 64, 0, stream>>>(cP, cL, carry);
  k_scanC<<<B_ * NCHUNK, 512, 0, stream>>>(dec, uu, gat, carry, outb);

  // K3: output GEMM -> fp32 y
  gemm8p<1><<<(M_ / 256) * (D_ / 256), 512, 0, stream>>>(
      outb, woutb, D_ / 256, y, nullptr, nullptr, nullptr, nullptr);
}